// Round 7
// baseline (44.870 us; speedup 1.0000x reference)
//
#include <hip/hip_runtime.h>

#define DD 128
#define FF 512
#define BAGS 5000

// Monotonic uint key for f32: preserves float ordering under unsigned compare.
__device__ __forceinline__ unsigned fkey(float f) {
    unsigned u = __float_as_uint(f);
    return (u & 0x80000000u) ? ~u : (u | 0x80000000u);
}
// Inverse of fkey (bijective).
__device__ __forceinline__ float fkey_inv(unsigned k) {
    unsigned u = (k & 0x80000000u) ? (k & 0x7FFFFFFFu) : ~k;
    return __uint_as_float(u);
}

// One block per bag, single dispatch, no workspace:
//   1) 2-lane binary search for the bag's row range [s,e) in sorted bag_idx
//   2) quad-lane matvec (4 lanes/row, 64 rows in flight), 2 shfl per row
//   3) 4-step wave suffix-max + LDS reduce of 4 wave partials (block = one bag)
//   4) gather argmax row of all arrays (zeros if empty); z row is L2-hot
__global__ __launch_bounds__(256) void fused_bag_kernel(
    const float* __restrict__ z, const int* __restrict__ bag,
    const float* __restrict__ inst, const float* __restrict__ mu,
    const float* __restrict__ stdv, const float* __restrict__ W,
    const float* __restrict__ b,
    float* __restrict__ oM, float* __restrict__ oInst, float* __restrict__ oZ,
    float* __restrict__ oMu, float* __restrict__ oStd, float* __restrict__ loc,
    int N)
{
    __shared__ int s_se[2];
    __shared__ unsigned long long s_best[4];

    int bagi = blockIdx.x;
    if (threadIdx.x < 2) {
        int target = bagi + (int)threadIdx.x;   // lower_bound(bag_idx, target)
        int lo = 0, hi = N;
        while (lo < hi) {
            int mid = (lo + hi) >> 1;
            if (bag[mid] < target) lo = mid + 1; else hi = mid;
        }
        s_se[threadIdx.x] = lo;
    }

    int tid  = threadIdx.x;
    int lane = tid & 63;
    int wave = tid >> 6;              // 0..3
    int ll   = lane & 3;              // quad position within row
    int rowslot = lane >> 4 == 0 ? (lane >> 2) : (lane >> 2); // 0..15
    int rslot = wave * 16 + (lane >> 2);    // 0..63: row offset within block tile

    float4 wk[8];                     // this lane's 8 W chunks (k = ll + 4j)
    #pragma unroll
    for (int j = 0; j < 8; ++j) wk[j] = ((const float4*)W)[ll + 4 * j];
    float bb = b[0];

    __syncthreads();
    int s = s_se[0], e = s_se[1];

    unsigned long long best = 0ull;
    for (long long row = s + rslot; row < e; row += 64) {
        const float4* zr = (const float4*)(z + row * DD);
        float4 acc = make_float4(0.f, 0.f, 0.f, 0.f);
        #pragma unroll
        for (int j = 0; j < 8; ++j) {
            float4 zv = zr[ll + 4 * j];
            acc.x = fmaf(zv.x, wk[j].x, acc.x);
            acc.y = fmaf(zv.y, wk[j].y, acc.y);
            acc.z = fmaf(zv.z, wk[j].z, acc.z);
            acc.w = fmaf(zv.w, wk[j].w, acc.w);
        }
        float sd = (acc.x + acc.y) + (acc.z + acc.w);
        sd += __shfl_xor(sd, 1, 64);  // quad-local, divergence-safe
        sd += __shfl_xor(sd, 2, 64);
        sd += bb;
        if (ll == 0) {
            loc[row] = sd;
            unsigned long long key =
                ((unsigned long long)fkey(sd) << 32) | (unsigned)(N - 1 - (int)row);
            if (key > best) best = key;
        }
    }
    // reduce across the 16 quad-heads of this wave (converged code)
    #pragma unroll
    for (int off = 4; off <= 32; off <<= 1) {
        unsigned long long o = __shfl_down(best, off, 64);
        if (o > best) best = o;
    }
    if (lane == 0) s_best[wave] = best;
    __syncthreads();
    if (tid == 0) {
        unsigned long long m = s_best[0];
        #pragma unroll
        for (int g = 1; g < 4; ++g) if (s_best[g] > m) m = s_best[g];
        s_best[0] = m;
    }
    __syncthreads();

    unsigned long long p = s_best[0];
    bool empty = (e <= s);
    long long ac = empty ? 0 : (long long)(N - 1 - (int)(unsigned)(p & 0xFFFFFFFFull));
    const float4 zero4 = make_float4(0.f, 0.f, 0.f, 0.f);
    int t = threadIdx.x;
    if (t < 128) {
        float4 v = empty ? zero4 : ((const float4*)(inst + ac * FF))[t];
        ((float4*)(oInst + (long long)bagi * FF))[t] = v;
    } else if (t < 160) {
        int k = t - 128;
        float4 v = empty ? zero4 : ((const float4*)(z + ac * DD))[k];
        ((float4*)(oZ + (long long)bagi * DD))[k] = v;
    } else if (t < 192) {
        int k = t - 160;
        float4 v = empty ? zero4 : ((const float4*)(mu + ac * DD))[k];
        ((float4*)(oMu + (long long)bagi * DD))[k] = v;
    } else if (t < 224) {
        int k = t - 192;
        float4 v = empty ? zero4 : ((const float4*)(stdv + ac * DD))[k];
        ((float4*)(oStd + (long long)bagi * DD))[k] = v;
    } else if (t == 224) {
        oM[bagi] = empty ? 0.f : fkey_inv((unsigned)(p >> 32));
    }
}

extern "C" void kernel_launch(void* const* d_in, const int* in_sizes, int n_in,
                              void* d_out, int out_size, void* d_ws, size_t ws_size,
                              hipStream_t stream) {
    const float* z    = (const float*)d_in[0];
    const int*   bag  = (const int*)d_in[1];
    const float* inst = (const float*)d_in[2];
    const float* mu   = (const float*)d_in[3];
    const float* stdv = (const float*)d_in[4];
    const float* W    = (const float*)d_in[5];
    const float* b    = (const float*)d_in[6];
    int N = in_sizes[1];

    float* out = (float*)d_out;
    // Output layout (flat, return order): M | max_instances | max_z_ins | loc_ins | mu | std
    long long off_inst = BAGS;
    long long off_z    = off_inst + (long long)BAGS * FF;
    long long off_loc  = off_z    + (long long)BAGS * DD;
    long long off_mu   = off_loc  + N;
    long long off_std  = off_mu   + (long long)BAGS * DD;

    fused_bag_kernel<<<BAGS, 256, 0, stream>>>(
        z, bag, inst, mu, stdv, W, b,
        out, out + off_inst, out + off_z, out + off_mu, out + off_std,
        out + off_loc, N);
}

// Round 8
// 40.747 us; speedup vs baseline: 1.1012x; 1.1012x over previous
//
#include <hip/hip_runtime.h>

#define DD 128
#define FF 512
#define BAGS 5000

// Monotonic uint key for f32: preserves float ordering under unsigned compare.
__device__ __forceinline__ unsigned fkey(float f) {
    unsigned u = __float_as_uint(f);
    return (u & 0x80000000u) ? ~u : (u | 0x80000000u);
}
// Inverse of fkey (bijective).
__device__ __forceinline__ float fkey_inv(unsigned k) {
    unsigned u = (k & 0x80000000u) ? (k & 0x7FFFFFFFu) : ~k;
    return __uint_as_float(u);
}

// loc = z@W + b with 8 lanes per row (octet): each dwordx4 load instruction
// covers 8 contiguous 128B segments (vs 16x64B for quad). 8 rows per wave-tile,
// 3 shfl_xor reduce per tile. Per-bag packed (fkey,idx) max via segmented
// suffix-max over the 8 row heads (bag_idx sorted), ~36K atomics total.
__global__ __launch_bounds__(256) void loc_seg_kernel(
    const float* __restrict__ z, const int* __restrict__ bag,
    const float* __restrict__ W, const float* __restrict__ b,
    float* __restrict__ loc, unsigned long long* __restrict__ packed, int N)
{
    int tid  = threadIdx.x;
    int lane = tid & 63;
    int wave = tid >> 6;              // 0..3
    int o    = lane & 7;              // octet position within row
    int rowslot = lane >> 3;          // 0..7

    long long wavebase = (long long)blockIdx.x * 256 + wave * 64;

    float4 wk[4];                     // this lane's 4 W chunks (k = o + 8j)
    #pragma unroll
    for (int j = 0; j < 4; ++j) wk[j] = ((const float4*)W)[o + 8 * j];
    float bb = b[0];

    #pragma unroll
    for (int t = 0; t < 8; ++t) {
        long long row = wavebase + t * 8 + rowslot;
        bool valid = row < N;
        float4 acc = make_float4(0.f, 0.f, 0.f, 0.f);
        if (valid) {
            const float4* zr = (const float4*)(z + row * DD);
            #pragma unroll
            for (int j = 0; j < 4; ++j) {
                float4 zv = zr[o + 8 * j];
                acc.x = fmaf(zv.x, wk[j].x, acc.x);
                acc.y = fmaf(zv.y, wk[j].y, acc.y);
                acc.z = fmaf(zv.z, wk[j].z, acc.z);
                acc.w = fmaf(zv.w, wk[j].w, acc.w);
            }
        }
        float sd = (acc.x + acc.y) + (acc.z + acc.w);
        sd += __shfl_xor(sd, 1, 64);   // octet-local reduce (converged code)
        sd += __shfl_xor(sd, 2, 64);
        sd += __shfl_xor(sd, 4, 64);
        sd += bb;

        int bl = -1;
        unsigned long long key = 0ull;
        if (valid && o == 0) {
            loc[row] = sd;
            bl = bag[row];
            key = ((unsigned long long)fkey(sd) << 32) | (unsigned)(N - 1 - (int)row);
        }
        // segmented suffix-max across the 8 row owners (lanes 0,8,...,56)
        #pragma unroll
        for (int off = 8; off <= 32; off <<= 1) {
            unsigned long long okey = __shfl_down(key, off, 64);
            int obag = __shfl_down(bl, off, 64);
            if (obag == bl && okey > key) key = okey;
        }
        int pbag = __shfl_up(bl, 8, 64);
        bool head = valid && (o == 0) && (rowslot == 0 || pbag != bl);
        if (head) atomicMax(&packed[bl], key);
    }
}

// One block per bag: copy the argmax row of each array (zeros if bag empty).
__global__ __launch_bounds__(256) void gather_kernel(
    const float* __restrict__ z, const float* __restrict__ inst,
    const float* __restrict__ mu, const float* __restrict__ stdv,
    const unsigned long long* __restrict__ packed,
    float* __restrict__ oM, float* __restrict__ oInst, float* __restrict__ oZ,
    float* __restrict__ oMu, float* __restrict__ oStd, int N)
{
    int bagi = blockIdx.x;
    unsigned long long p = packed[bagi];
    bool empty = (p == 0ull);
    long long ac = empty ? 0 : (long long)(N - 1 - (int)(unsigned)(p & 0xFFFFFFFFull));
    const float4 zero4 = make_float4(0.f, 0.f, 0.f, 0.f);
    int t = threadIdx.x;
    if (t < 128) {
        float4 v = empty ? zero4 : ((const float4*)(inst + ac * FF))[t];
        ((float4*)(oInst + (long long)bagi * FF))[t] = v;
    } else if (t < 160) {
        int k = t - 128;
        float4 v = empty ? zero4 : ((const float4*)(z + ac * DD))[k];
        ((float4*)(oZ + (long long)bagi * DD))[k] = v;
    } else if (t < 192) {
        int k = t - 160;
        float4 v = empty ? zero4 : ((const float4*)(mu + ac * DD))[k];
        ((float4*)(oMu + (long long)bagi * DD))[k] = v;
    } else if (t < 224) {
        int k = t - 192;
        float4 v = empty ? zero4 : ((const float4*)(stdv + ac * DD))[k];
        ((float4*)(oStd + (long long)bagi * DD))[k] = v;
    } else if (t == 224) {
        oM[bagi] = empty ? 0.f : fkey_inv((unsigned)(p >> 32));
    }
}

extern "C" void kernel_launch(void* const* d_in, const int* in_sizes, int n_in,
                              void* d_out, int out_size, void* d_ws, size_t ws_size,
                              hipStream_t stream) {
    const float* z    = (const float*)d_in[0];
    const int*   bag  = (const int*)d_in[1];
    const float* inst = (const float*)d_in[2];
    const float* mu   = (const float*)d_in[3];
    const float* stdv = (const float*)d_in[4];
    const float* W    = (const float*)d_in[5];
    const float* b    = (const float*)d_in[6];
    int N = in_sizes[1];

    float* out = (float*)d_out;
    // Output layout (flat, return order): M | max_instances | max_z_ins | loc_ins | mu | std
    long long off_inst = BAGS;
    long long off_z    = off_inst + (long long)BAGS * FF;
    long long off_loc  = off_z    + (long long)BAGS * DD;
    long long off_mu   = off_loc  + N;
    long long off_std  = off_mu   + (long long)BAGS * DD;

    unsigned long long* packed = (unsigned long long*)d_ws;
    float* loc = out + off_loc;

    hipMemsetAsync(packed, 0, BAGS * sizeof(unsigned long long), stream);
    int blocks = (N + 255) / 256;
    loc_seg_kernel<<<blocks, 256, 0, stream>>>(z, bag, W, b, loc, packed, N);
    gather_kernel<<<BAGS, 256, 0, stream>>>(z, inst, mu, stdv, packed,
                                            out, out + off_inst, out + off_z,
                                            out + off_mu, out + off_std, N);
}

// Round 9
// 40.239 us; speedup vs baseline: 1.1151x; 1.0126x over previous
//
#include <hip/hip_runtime.h>

#define DD 128
#define FF 512
#define BAGS 5000

// Monotonic uint key for f32: preserves float ordering under unsigned compare.
__device__ __forceinline__ unsigned fkey(float f) {
    unsigned u = __float_as_uint(f);
    return (u & 0x80000000u) ? ~u : (u | 0x80000000u);
}
// Inverse of fkey (bijective).
__device__ __forceinline__ float fkey_inv(unsigned k) {
    unsigned u = (k & 0x80000000u) ? (k & 0x7FFFFFFFu) : ~k;
    return __uint_as_float(u);
}

// loc = z@W + b, 8 lanes per row (octet), 64 rows per wave.
// Epilogue per wave: ONE coalesced 256B loc store, ONE coalesced bag load,
// ONE 6-step segmented suffix-max over 64 row slots, lane0-always-head +
// bag-change heads -> ~9K atomicMax total.
__global__ __launch_bounds__(256) void loc_seg_kernel(
    const float* __restrict__ z, const int* __restrict__ bag,
    const float* __restrict__ W, const float* __restrict__ b,
    float* __restrict__ loc, unsigned long long* __restrict__ packed, int N)
{
    int tid  = threadIdx.x;
    int lane = tid & 63;
    int wave = tid >> 6;              // 0..3
    int o    = lane & 7;              // octet position within row
    int rowslot = lane >> 3;          // 0..7

    long long rowbase = (long long)blockIdx.x * 256 + wave * 64;

    float4 wk[4];                     // this lane's 4 W chunks (k = o + 8j)
    #pragma unroll
    for (int j = 0; j < 4; ++j) wk[j] = ((const float4*)W)[o + 8 * j];
    float bb = b[0];

    float myloc = 0.f;
    #pragma unroll
    for (int t = 0; t < 8; ++t) {
        long long row = rowbase + t * 8 + rowslot;
        float4 acc = make_float4(0.f, 0.f, 0.f, 0.f);
        if (row < N) {
            const float4* zr = (const float4*)(z + row * DD);
            #pragma unroll
            for (int j = 0; j < 4; ++j) {
                float4 zv = zr[o + 8 * j];
                acc.x = fmaf(zv.x, wk[j].x, acc.x);
                acc.y = fmaf(zv.y, wk[j].y, acc.y);
                acc.z = fmaf(zv.z, wk[j].z, acc.z);
                acc.w = fmaf(zv.w, wk[j].w, acc.w);
            }
        }
        float sd = (acc.x + acc.y) + (acc.z + acc.w);
        sd += __shfl_xor(sd, 1, 64);   // octet-local reduce (all 8 lanes get it)
        sd += __shfl_xor(sd, 2, 64);
        sd += __shfl_xor(sd, 4, 64);
        // lane l wants row rowbase+l = tile (l>>3), slot (l&7); that value
        // lives in lanes (l&7)*8 .. (l&7)*8+7
        float v = __shfl(sd, (lane & 7) * 8, 64);
        if (t == (lane >> 3)) myloc = v;
    }

    long long row = rowbase + lane;
    bool valid = row < N;
    myloc += bb;
    int bl = -1;
    unsigned long long key = 0ull;
    if (valid) {
        loc[row] = myloc;                       // coalesced 256B per wave
        bl = bag[row];                          // coalesced 256B per wave
        key = ((unsigned long long)fkey(myloc) << 32) | (unsigned)(N - 1 - (int)row);
    }
    // segmented suffix-max over 64 row slots (bl constant per lane => classic
    // doubling segmented reduce; invalid lanes have bl=-1, never merge)
    #pragma unroll
    for (int off = 1; off <= 32; off <<= 1) {
        int src = lane + off;
        int clamped = src < 64 ? src : lane;
        unsigned long long okey = __shfl(key, clamped, 64);
        int obag = __shfl(bl, clamped, 64);
        if (src < 64 && obag == bl && okey > key) key = okey;
    }
    int pb = __shfl(bl, lane > 0 ? lane - 1 : 0, 64);
    bool head = valid && (lane == 0 || pb != bl);  // lane0-always-head: coverage exact
    if (head) atomicMax(&packed[bl], key);
}

// One block per bag: copy the argmax row of each array (zeros if bag empty).
__global__ __launch_bounds__(256) void gather_kernel(
    const float* __restrict__ z, const float* __restrict__ inst,
    const float* __restrict__ mu, const float* __restrict__ stdv,
    const unsigned long long* __restrict__ packed,
    float* __restrict__ oM, float* __restrict__ oInst, float* __restrict__ oZ,
    float* __restrict__ oMu, float* __restrict__ oStd, int N)
{
    int bagi = blockIdx.x;
    unsigned long long p = packed[bagi];
    bool empty = (p == 0ull);
    long long ac = empty ? 0 : (long long)(N - 1 - (int)(unsigned)(p & 0xFFFFFFFFull));
    const float4 zero4 = make_float4(0.f, 0.f, 0.f, 0.f);
    int t = threadIdx.x;
    if (t < 128) {
        float4 v = empty ? zero4 : ((const float4*)(inst + ac * FF))[t];
        ((float4*)(oInst + (long long)bagi * FF))[t] = v;
    } else if (t < 160) {
        int k = t - 128;
        float4 v = empty ? zero4 : ((const float4*)(z + ac * DD))[k];
        ((float4*)(oZ + (long long)bagi * DD))[k] = v;
    } else if (t < 192) {
        int k = t - 160;
        float4 v = empty ? zero4 : ((const float4*)(mu + ac * DD))[k];
        ((float4*)(oMu + (long long)bagi * DD))[k] = v;
    } else if (t < 224) {
        int k = t - 192;
        float4 v = empty ? zero4 : ((const float4*)(stdv + ac * DD))[k];
        ((float4*)(oStd + (long long)bagi * DD))[k] = v;
    } else if (t == 224) {
        oM[bagi] = empty ? 0.f : fkey_inv((unsigned)(p >> 32));
    }
}

extern "C" void kernel_launch(void* const* d_in, const int* in_sizes, int n_in,
                              void* d_out, int out_size, void* d_ws, size_t ws_size,
                              hipStream_t stream) {
    const float* z    = (const float*)d_in[0];
    const int*   bag  = (const int*)d_in[1];
    const float* inst = (const float*)d_in[2];
    const float* mu   = (const float*)d_in[3];
    const float* stdv = (const float*)d_in[4];
    const float* W    = (const float*)d_in[5];
    const float* b    = (const float*)d_in[6];
    int N = in_sizes[1];

    float* out = (float*)d_out;
    // Output layout (flat, return order): M | max_instances | max_z_ins | loc_ins | mu | std
    long long off_inst = BAGS;
    long long off_z    = off_inst + (long long)BAGS * FF;
    long long off_loc  = off_z    + (long long)BAGS * DD;
    long long off_mu   = off_loc  + N;
    long long off_std  = off_mu   + (long long)BAGS * DD;

    unsigned long long* packed = (unsigned long long*)d_ws;
    float* loc = out + off_loc;

    hipMemsetAsync(packed, 0, BAGS * sizeof(unsigned long long), stream);
    int blocks = (N + 255) / 256;
    loc_seg_kernel<<<blocks, 256, 0, stream>>>(z, bag, W, b, loc, packed, N);
    gather_kernel<<<BAGS, 256, 0, stream>>>(z, inst, mu, stdv, packed,
                                            out, out + off_inst, out + off_z,
                                            out + off_mu, out + off_std, N);
}